// Round 1
// baseline (1366.224 us; speedup 1.0000x reference)
//
#include <hip/hip_runtime.h>
#include <hip/hip_bf16.h>

#define DEVI __device__ __forceinline__

typedef __bf16 bfrag __attribute__((ext_vector_type(8)));
typedef unsigned short us8 __attribute__((ext_vector_type(8)));
typedef float f32x4 __attribute__((ext_vector_type(4)));

static constexpr int NB  = 16;    // batch
static constexpr int NH  = 8;     // heads
static constexpr int DIM = 1024;  // model dim
static constexpr int DQh = 128;   // per-head dim
static constexpr int ST  = 1024;  // target len
static constexpr int SM  = 2048;  // memory len
static constexpr float INV_SCALE = 0.29730177875068026f; // 1 / 128^0.25
static constexpr float LN_EPS = 1e-5f;

DEVI unsigned short f2bf(float f) {
  __hip_bfloat16 h = __float2bfloat16(f);
  return __builtin_bit_cast(unsigned short, h);
}
DEVI bfrag ldfrag(const unsigned short* p) {
  return __builtin_bit_cast(bfrag, *(const us8*)p);
}

enum { EPI_NONE = 0, EPI_ADD = 1, EPI_SWISH = 2 };

// ---------------------------------------------------------------------------
// Generic GEMM: C[M][N] = A[M][K] (f32, row-major) x Bt[N][K] (TB = ushort
// (bf16 bits) or f32). 128x128 tile, BK=32, 4 waves (2x2 of 64x64), MFMA
// 16x16x32 bf16. Optional residual-add / swish epilogue; optional scrambled
// store implementing the torch .view(b, w, h*d) head-merge.
// ---------------------------------------------------------------------------
template<typename TB, int EPI, bool SCRAMBLE>
__global__ __launch_bounds__(256, 2)
void gemm_rm(const float* __restrict__ A, const TB* __restrict__ Bt,
             const float* __restrict__ Res, float* __restrict__ C,
             int M, int N, int K, long aZ, long bZ, long cZ)
{
  __shared__ unsigned short As[128][40]; // stride 80B = 5*16B: aligned b128 reads
  __shared__ unsigned short Bs[128][40];
  const int tid = threadIdx.x;
  const int z   = blockIdx.z;
  const int m0  = blockIdx.y * 128;
  const int n0  = blockIdx.x * 128;
  A  += aZ * (long)z + (long)m0 * K;
  Bt += bZ * (long)z + (long)n0 * K;

  const int lane = tid & 63;
  const int wr   = ((tid >> 6) >> 1) * 64;
  const int wc   = ((tid >> 6) & 1) * 64;
  const int frow = lane & 15;
  const int fk   = (lane >> 4) * 8;

  f32x4 acc[4][4];
  #pragma unroll
  for (int i = 0; i < 4; ++i)
    #pragma unroll
    for (int j = 0; j < 4; ++j) acc[i][j] = f32x4{0.f, 0.f, 0.f, 0.f};

  const int akk = (tid & 7) * 4;  // float4 k-offset
  const int ar  = tid >> 3;       // 0..31

  for (int k0 = 0; k0 < K; k0 += 32) {
    __syncthreads();
    // stage A (f32 -> bf16)
    #pragma unroll
    for (int p = 0; p < 4; ++p) {
      const int r = ar + p * 32;
      const float4 v = *(const float4*)(A + (long)r * K + k0 + akk);
      ushort4 sv = make_ushort4(f2bf(v.x), f2bf(v.y), f2bf(v.z), f2bf(v.w));
      *(ushort4*)&As[r][akk] = sv;
    }
    // stage B
    if constexpr (sizeof(TB) == 2) {
      const int bc = (tid & 3) * 8;
      const int bn = tid >> 2;  // 0..63
      #pragma unroll
      for (int p = 0; p < 2; ++p) {
        const int n = bn + p * 64;
        const uint4 v = *(const uint4*)((const unsigned short*)Bt + (long)n * K + k0 + bc);
        *(uint4*)&Bs[n][bc] = v;
      }
    } else {
      #pragma unroll
      for (int p = 0; p < 4; ++p) {
        const int r = ar + p * 32;
        const float4 v = *(const float4*)((const float*)Bt + (long)r * K + k0 + akk);
        ushort4 sv = make_ushort4(f2bf(v.x), f2bf(v.y), f2bf(v.z), f2bf(v.w));
        *(ushort4*)&Bs[r][akk] = sv;
      }
    }
    __syncthreads();
    bfrag af[4], bfv[4];
    #pragma unroll
    for (int i = 0; i < 4; ++i) af[i]  = ldfrag(&As[wr + i * 16 + frow][fk]);
    #pragma unroll
    for (int j = 0; j < 4; ++j) bfv[j] = ldfrag(&Bs[wc + j * 16 + frow][fk]);
    #pragma unroll
    for (int i = 0; i < 4; ++i)
      #pragma unroll
      for (int j = 0; j < 4; ++j)
        acc[i][j] = __builtin_amdgcn_mfma_f32_16x16x32_bf16(af[i], bfv[j], acc[i][j], 0, 0, 0);
  }

  const int rb = (lane >> 4) * 4;
  #pragma unroll
  for (int i = 0; i < 4; ++i) {
    #pragma unroll
    for (int j = 0; j < 4; ++j) {
      #pragma unroll
      for (int e = 0; e < 4; ++e) {
        const int gm = m0 + wr + i * 16 + rb + e;
        const int gn = n0 + wc + j * 16 + frow;
        float val = acc[i][j][e];
        if constexpr (EPI == EPI_ADD)   val += Res[(long)gm * N + gn];
        if constexpr (EPI == EPI_SWISH) val = val / (1.0f + __expf(-val));
        if constexpr (SCRAMBLE) {
          // z = h*16+b; Bm[b,h,w,d] -> out[b, h*128 + w/8, (w%8)*128 + d]
          const int b = z & 15, h = z >> 4;
          C[(long)b * (ST * DIM) + (long)(h * 128 + (gm >> 3)) * DIM + (gm & 7) * 128 + gn] = val;
        } else {
          C[cZ * (long)z + (long)gm * N + gn] = val;
        }
      }
    }
  }
}

// ---------------------------------------------------------------------------
// AmatT[z][e][d] = sum_s V[z][s][e] * softK[z][s][d]   (z = h*NB + b)
// Both operands stored [s][128]; LDS-transpose staging. One block per z.
// ---------------------------------------------------------------------------
__global__ __launch_bounds__(256, 2)
void gemm_ktv(const float* __restrict__ Kp, const float* __restrict__ Vp,
              float* __restrict__ AT, int S)
{
  __shared__ unsigned short As[128][40]; // Vt[e][s']
  __shared__ unsigned short Bs[128][40]; // Kt[d][s']
  const int tid = threadIdx.x;
  const int z = blockIdx.x;
  const float* Vb = Vp + (long)z * S * DQh;
  const float* Kb = Kp + (long)z * S * DQh;
  const int lane = tid & 63;
  const int wr = ((tid >> 6) >> 1) * 64, wc = ((tid >> 6) & 1) * 64;
  const int frow = lane & 15, fk = (lane >> 4) * 8;
  const int c = tid & 127;    // column index (e or d)
  const int sr0 = tid >> 7;   // 0..1

  f32x4 acc[4][4];
  #pragma unroll
  for (int i = 0; i < 4; ++i)
    #pragma unroll
    for (int j = 0; j < 4; ++j) acc[i][j] = f32x4{0.f, 0.f, 0.f, 0.f};

  for (int s0 = 0; s0 < S; s0 += 32) {
    __syncthreads();
    #pragma unroll
    for (int p = 0; p < 16; ++p) {
      const int sr = sr0 + p * 2;
      As[c][sr] = f2bf(Vb[(long)(s0 + sr) * DQh + c]);
      Bs[c][sr] = f2bf(Kb[(long)(s0 + sr) * DQh + c]);
    }
    __syncthreads();
    bfrag af[4], bfv[4];
    #pragma unroll
    for (int i = 0; i < 4; ++i) af[i]  = ldfrag(&As[wr + i * 16 + frow][fk]);
    #pragma unroll
    for (int j = 0; j < 4; ++j) bfv[j] = ldfrag(&Bs[wc + j * 16 + frow][fk]);
    #pragma unroll
    for (int i = 0; i < 4; ++i)
      #pragma unroll
      for (int j = 0; j < 4; ++j)
        acc[i][j] = __builtin_amdgcn_mfma_f32_16x16x32_bf16(af[i], bfv[j], acc[i][j], 0, 0, 0);
  }
  const int rb = (lane >> 4) * 4;
  #pragma unroll
  for (int i = 0; i < 4; ++i)
    #pragma unroll
    for (int j = 0; j < 4; ++j)
      #pragma unroll
      for (int e = 0; e < 4; ++e)
        AT[(long)z * 16384 + (long)(wr + i * 16 + rb + e) * 128 + (wc + j * 16 + frow)] =
            acc[i][j][e];
}

// ---------------------------------------------------------------------------
// Row softmax over 128 (head-dim), in place, with optional causal-style mask
// over the head-dim (mask: d > (row % ST) -> -inf). One wave per row.
// ---------------------------------------------------------------------------
template<bool MASKED>
__global__ __launch_bounds__(256)
void softmax128(float* __restrict__ X)
{
  const int row = blockIdx.x * 4 + (threadIdx.x >> 6);
  const int lane = threadIdx.x & 63;
  float* xr = X + (long)row * 128;
  float x0 = xr[lane] * INV_SCALE;
  float x1 = xr[lane + 64] * INV_SCALE;
  if constexpr (MASKED) {
    const int s = row & (ST - 1);
    if (lane > s)      x0 = -3.0e38f;
    if (lane + 64 > s) x1 = -3.0e38f;
  }
  float mx = fmaxf(x0, x1);
  #pragma unroll
  for (int o = 32; o; o >>= 1) mx = fmaxf(mx, __shfl_xor(mx, o));
  const float e0 = __expf(x0 - mx);
  const float e1 = __expf(x1 - mx);
  float sm = e0 + e1;
  #pragma unroll
  for (int o = 32; o; o >>= 1) sm += __shfl_xor(sm, o);
  const float inv = 1.0f / sm;
  xr[lane]      = e0 * inv;
  xr[lane + 64] = e1 * inv;
}

// ---------------------------------------------------------------------------
// LayerNorm over DIM=1024, one block per row, in-place safe.
// ---------------------------------------------------------------------------
__global__ __launch_bounds__(256)
void layernorm_k(const float* __restrict__ X, const float* __restrict__ G,
                 const float* __restrict__ Bta, float* __restrict__ Y)
{
  const int row = blockIdx.x;
  const int t = threadIdx.x;
  const float4 v = *(const float4*)(X + (long)row * DIM + t * 4);
  float s  = v.x + v.y + v.z + v.w;
  float sq = v.x * v.x + v.y * v.y + v.z * v.z + v.w * v.w;
  #pragma unroll
  for (int o = 32; o; o >>= 1) { s += __shfl_xor(s, o); sq += __shfl_xor(sq, o); }
  __shared__ float ps[4], pq[4];
  if ((t & 63) == 0) { ps[t >> 6] = s; pq[t >> 6] = sq; }
  __syncthreads();
  s  = ps[0] + ps[1] + ps[2] + ps[3];
  sq = pq[0] + pq[1] + pq[2] + pq[3];
  const float mean = s * (1.0f / DIM);
  const float var  = sq * (1.0f / DIM) - mean * mean;
  const float rstd = rsqrtf(var + LN_EPS);
  const float4 gv = *(const float4*)(G + t * 4);
  const float4 bv = *(const float4*)(Bta + t * 4);
  float4 o;
  o.x = (v.x - mean) * rstd * gv.x + bv.x;
  o.y = (v.y - mean) * rstd * gv.y + bv.y;
  o.z = (v.z - mean) * rstd * gv.z + bv.z;
  o.w = (v.w - mean) * rstd * gv.w + bv.w;
  *(float4*)(Y + (long)row * DIM + t * 4) = o;
}

// ---------------------------------------------------------------------------
// Weight prep: [H][DIM][DQh] f32 -> [H][DQh][DIM] bf16 (transpose+cast)
// ---------------------------------------------------------------------------
__global__ __launch_bounds__(256)
void transpose_cast(const float* __restrict__ W, unsigned short* __restrict__ Wt)
{
  __shared__ float tile[32][33];
  const int z = blockIdx.z;
  const int kb = blockIdx.y * 32;  // DIM tile
  const int nb = blockIdx.x * 32;  // DQh tile
  const float* src = W + (long)z * DIM * DQh;
  unsigned short* dst = Wt + (long)z * DIM * DQh;
  const int tx = threadIdx.x & 31;
  const int ty = threadIdx.x >> 5;
  #pragma unroll
  for (int r = 0; r < 32; r += 8)
    tile[ty + r][tx] = src[(long)(kb + ty + r) * DQh + nb + tx];
  __syncthreads();
  #pragma unroll
  for (int r = 0; r < 32; r += 8)
    dst[(long)(nb + ty + r) * DIM + kb + tx] = f2bf(tile[tx][ty + r]);
}

// plain f32 -> bf16 cast; grid*1024 == n exactly
__global__ __launch_bounds__(256)
void cast_bf16(const float* __restrict__ X, unsigned short* __restrict__ Yq)
{
  const int i = (blockIdx.x * 256 + threadIdx.x) * 4;
  const float4 v = *(const float4*)(X + i);
  ushort4 sv = make_ushort4(f2bf(v.x), f2bf(v.y), f2bf(v.z), f2bf(v.w));
  *(ushort4*)(Yq + i) = sv;
}

// ---------------------------------------------------------------------------

extern "C" void kernel_launch(void* const* d_in, const int* in_sizes, int n_in,
                              void* d_out, int out_size, void* d_ws, size_t ws_size,
                              hipStream_t stream)
{
  (void)in_sizes; (void)n_in; (void)out_size; (void)ws_size;
  const float* mem = (const float*)d_in[0];
  const float* y0  = (const float*)d_in[1];
  const float* Wq1 = (const float*)d_in[2];
  const float* Wk1 = (const float*)d_in[3];
  const float* Wv1 = (const float*)d_in[4];
  const float* Wo1 = (const float*)d_in[5];
  const float* Wq2 = (const float*)d_in[6];
  const float* Wk2 = (const float*)d_in[7];
  const float* Wv2 = (const float*)d_in[8];
  const float* Wo2 = (const float*)d_in[9];
  const float* E1  = (const float*)d_in[10];
  const float* D1  = (const float*)d_in[11];
  const float* E2  = (const float*)d_in[12];
  const float* D2  = (const float*)d_in[13];
  const float* g1  = (const float*)d_in[14];
  const float* b1  = (const float*)d_in[15];
  const float* g2  = (const float*)d_in[16];
  const float* b2  = (const float*)d_in[17];
  const float* g3  = (const float*)d_in[18];
  const float* b3  = (const float*)d_in[19];

  char* ws = (char*)d_ws;
  const size_t MB = 1ull << 20;
  unsigned short* wq1t = (unsigned short*)(ws + 0 * MB);
  unsigned short* wk1t = (unsigned short*)(ws + 2 * MB);
  unsigned short* wv1t = (unsigned short*)(ws + 4 * MB);
  unsigned short* wq2t = (unsigned short*)(ws + 6 * MB);
  unsigned short* wk2t = (unsigned short*)(ws + 8 * MB);
  unsigned short* wv2t = (unsigned short*)(ws + 10 * MB);
  unsigned short* wo1b = (unsigned short*)(ws + 12 * MB);
  unsigned short* wo2b = (unsigned short*)(ws + 14 * MB);
  unsigned short* e1b  = (unsigned short*)(ws + 16 * MB);
  unsigned short* d1b  = (unsigned short*)(ws + 17 * MB);
  unsigned short* e2b  = (unsigned short*)(ws + 18 * MB);
  unsigned short* d2b  = (unsigned short*)(ws + 19 * MB);
  float* qbuf  = (float*)(ws + 20 * MB);   // [H][B][ST][DQ]   64 MB
  float* kbuf  = (float*)(ws + 84 * MB);   // [H][B][S][DQ]   128 MB (max SM)
  float* vbuf  = (float*)(ws + 212 * MB);  //                 128 MB
  float* amatT = (float*)(ws + 340 * MB);  // [H*B][128][128]   8 MB
  float* attn  = (float*)(ws + 348 * MB);  // [B][ST][DIM]     64 MB
  float* ybuf  = (float*)(ws + 412 * MB);  // [B*ST][DIM]      64 MB
  float* bnbuf = attn;                     // reuse in LFFN
  float* hbuf  = qbuf;                     // reuse in LFFN

  const long PZB = (long)DQh * DIM;        // per-head weight stride (elements)
  const long QZC = (long)NB * ST * DQh;    // per-head q/k/v stride (S=ST)
  const long KZC2 = (long)NB * SM * DQh;   // per-head k/v stride (S=SM)

  // ---- weight prep ----
  transpose_cast<<<dim3(4, 32, 8), 256, 0, stream>>>(Wq1, wq1t);
  transpose_cast<<<dim3(4, 32, 8), 256, 0, stream>>>(Wk1, wk1t);
  transpose_cast<<<dim3(4, 32, 8), 256, 0, stream>>>(Wv1, wv1t);
  transpose_cast<<<dim3(4, 32, 8), 256, 0, stream>>>(Wq2, wq2t);
  transpose_cast<<<dim3(4, 32, 8), 256, 0, stream>>>(Wk2, wk2t);
  transpose_cast<<<dim3(4, 32, 8), 256, 0, stream>>>(Wv2, wv2t);
  cast_bf16<<<1024, 256, 0, stream>>>(Wo1, wo1b);
  cast_bf16<<<1024, 256, 0, stream>>>(Wo2, wo2b);
  cast_bf16<<<512, 256, 0, stream>>>(E1, e1b);
  cast_bf16<<<512, 256, 0, stream>>>(D1, d1b);
  cast_bf16<<<512, 256, 0, stream>>>(E2, e2b);
  cast_bf16<<<512, 256, 0, stream>>>(D2, d2b);

  // ---- phase 1: masked self linear-attention ----
  gemm_rm<unsigned short, EPI_NONE, false><<<dim3(1, 128, 8), 256, 0, stream>>>(
      y0, wq1t, nullptr, qbuf, NB * ST, DQh, DIM, 0, PZB, QZC);
  gemm_rm<unsigned short, EPI_NONE, false><<<dim3(1, 128, 8), 256, 0, stream>>>(
      y0, wk1t, nullptr, kbuf, NB * ST, DQh, DIM, 0, PZB, QZC);
  gemm_rm<unsigned short, EPI_NONE, false><<<dim3(1, 128, 8), 256, 0, stream>>>(
      y0, wv1t, nullptr, vbuf, NB * ST, DQh, DIM, 0, PZB, QZC);
  softmax128<true><<<NH * NB * ST / 4, 256, 0, stream>>>(qbuf);
  softmax128<false><<<NH * NB * ST / 4, 256, 0, stream>>>(kbuf);
  gemm_ktv<<<NH * NB, 256, 0, stream>>>(kbuf, vbuf, amatT, ST);
  gemm_rm<float, EPI_NONE, true><<<dim3(1, 8, 128), 256, 0, stream>>>(
      qbuf, amatT, nullptr, attn, ST, DQh, DQh, (long)ST * DQh, 16384, 0);
  gemm_rm<unsigned short, EPI_ADD, false><<<dim3(8, 128, 1), 256, 0, stream>>>(
      attn, wo1b, y0, ybuf, NB * ST, DIM, DIM, 0, 0, 0);
  layernorm_k<<<NB * ST, 256, 0, stream>>>(ybuf, g1, b1, ybuf);

  // ---- phase 2: cross linear-attention with memory ----
  gemm_rm<unsigned short, EPI_NONE, false><<<dim3(1, 128, 8), 256, 0, stream>>>(
      ybuf, wq2t, nullptr, qbuf, NB * ST, DQh, DIM, 0, PZB, QZC);
  gemm_rm<unsigned short, EPI_NONE, false><<<dim3(1, 256, 8), 256, 0, stream>>>(
      mem, wk2t, nullptr, kbuf, NB * SM, DQh, DIM, 0, PZB, KZC2);
  gemm_rm<unsigned short, EPI_NONE, false><<<dim3(1, 256, 8), 256, 0, stream>>>(
      mem, wv2t, nullptr, vbuf, NB * SM, DQh, DIM, 0, PZB, KZC2);
  softmax128<false><<<NH * NB * ST / 4, 256, 0, stream>>>(qbuf);
  softmax128<false><<<NH * NB * SM / 4, 256, 0, stream>>>(kbuf);
  gemm_ktv<<<NH * NB, 256, 0, stream>>>(kbuf, vbuf, amatT, SM);
  gemm_rm<float, EPI_NONE, true><<<dim3(1, 8, 128), 256, 0, stream>>>(
      qbuf, amatT, nullptr, attn, ST, DQh, DQh, (long)ST * DQh, 16384, 0);
  gemm_rm<unsigned short, EPI_ADD, false><<<dim3(8, 128, 1), 256, 0, stream>>>(
      attn, wo2b, ybuf, ybuf, NB * ST, DIM, DIM, 0, 0, 0);
  layernorm_k<<<NB * ST, 256, 0, stream>>>(ybuf, g2, b2, ybuf);

  // ---- phase 3: LFFN ----
  gemm_rm<unsigned short, EPI_NONE, false><<<dim3(4, 128, 1), 256, 0, stream>>>(
      ybuf, e1b, nullptr, bnbuf, NB * ST, 512, DIM, 0, 0, 0);
  gemm_rm<unsigned short, EPI_SWISH, false><<<dim3(8, 128, 1), 256, 0, stream>>>(
      bnbuf, d1b, nullptr, hbuf, NB * ST, DIM, 512, 0, 0, 0);
  gemm_rm<unsigned short, EPI_NONE, false><<<dim3(4, 128, 1), 256, 0, stream>>>(
      hbuf, e2b, nullptr, bnbuf, NB * ST, 512, DIM, 0, 0, 0);
  gemm_rm<unsigned short, EPI_ADD, false><<<dim3(8, 128, 1), 256, 0, stream>>>(
      bnbuf, d2b, ybuf, ybuf, NB * ST, DIM, 512, 0, 0, 0);
  layernorm_k<<<NB * ST, 256, 0, stream>>>(ybuf, g3, b3, (float*)d_out);
}

// Round 2
// 1006.928 us; speedup vs baseline: 1.3568x; 1.3568x over previous
//
#include <hip/hip_runtime.h>
#include <hip/hip_bf16.h>

#define DEVI __device__ __forceinline__

typedef __bf16 bfrag __attribute__((ext_vector_type(8)));
typedef unsigned short us8 __attribute__((ext_vector_type(8)));
typedef float f32x4 __attribute__((ext_vector_type(4)));
typedef unsigned short ushort_t;

static constexpr int NB  = 16;
static constexpr int NH  = 8;
static constexpr int DIM = 1024;
static constexpr int DQh = 128;
static constexpr int ST  = 1024;
static constexpr int SM  = 2048;
static constexpr float INV_SCALE = 0.29730177875068026f; // 1 / 128^0.25
static constexpr float LN_EPS = 1e-5f;

DEVI ushort_t f2bf(float f) {
  __hip_bfloat16 h = __float2bfloat16(f);
  return __builtin_bit_cast(ushort_t, h);
}
DEVI float bf2f(ushort_t u) {
  return __bfloat162float(__builtin_bit_cast(__hip_bfloat16, u));
}
DEVI bfrag ldfrag(const ushort_t* p) {
  return __builtin_bit_cast(bfrag, *(const us8*)p);
}
DEVI void gl16(const ushort_t* g, ushort_t* l) {
  __builtin_amdgcn_global_load_lds(
      (const __attribute__((address_space(1))) void*)g,
      (__attribute__((address_space(3))) void*)l, 16, 0, 0);
}

enum { ST_BF16 = 0, ST_SWISH = 1, ST_F32RES = 2, ST_SCR = 3, ST_QKV = 4 };

// ---------------------------------------------------------------------------
// bf16 x bf16 GEMM: C = A[M][K] x Bt[N][K]^T. 128x128 tile, BK=32, 4 waves,
// global_load_lds(16) staging with XOR-swizzled source/read (conflict fix).
// Store variants: plain bf16 (+swish), f32 + residual, head-merge scramble,
// QKV scatter to [z=h*16+b][s][dq] buffers.
// ---------------------------------------------------------------------------
template<int STORE>
__global__ __launch_bounds__(256, 2)
void gemm_bb(const ushort_t* __restrict__ A, const ushort_t* __restrict__ Bt,
             const float* __restrict__ Res,
             ushort_t* __restrict__ Q0, ushort_t* __restrict__ Q1,
             ushort_t* __restrict__ Q2, float* __restrict__ Cf,
             int M, int N, int K, long aZ, long bZ, int logS)
{
  __shared__ ushort_t As[128][32];
  __shared__ ushort_t Bs[128][32];
  const int tid = threadIdx.x;
  int bx = blockIdx.x, by = blockIdx.y;
  if (gridDim.z == 1) {
    const int gx = gridDim.x;
    const int nwg = gx * gridDim.y;
    int bid = by * gx + bx;
    if ((nwg & 7) == 0) bid = (bid & 7) * (nwg >> 3) + (bid >> 3);  // XCD swizzle
    bx = bid % gx; by = bid / gx;
  }
  const int z = blockIdx.z;
  const int m0 = by * 128, n0 = bx * 128;
  A  += aZ * (long)z;
  Bt += bZ * (long)z;

  const int lane = tid & 63;
  const int w = tid >> 6;
  const int wr = (w >> 1) * 64, wc = (w & 1) * 64;
  const int frow = lane & 15;

  // staging: wave w owns rows [w*32, w*32+32); lane -> row w*32+h*16+(lane>>2),
  // k-granule (lane&3); source k pre-swizzled so swizzled reads see linear data
  const int grow = lane >> 2;
  const int gk = ((lane & 3) ^ ((lane >> 3) & 3)) * 8;
  const ushort_t* Ag = A + (long)(m0 + w * 32 + grow) * K + gk;
  const ushort_t* Bg = Bt + (long)(n0 + w * 32 + grow) * K + gk;

  f32x4 acc[4][4];
  #pragma unroll
  for (int i = 0; i < 4; ++i)
    #pragma unroll
    for (int j = 0; j < 4; ++j) acc[i][j] = f32x4{0.f, 0.f, 0.f, 0.f};

  const int kqs = ((frow >> 1) & 3);  // read-side XOR term (row&15 == frow)
  for (int k0 = 0; k0 < K; k0 += 32) {
    __syncthreads();
    gl16(Ag + k0,               &As[w * 32][0]);
    gl16(Ag + k0 + (long)16 * K, &As[w * 32 + 16][0]);
    gl16(Bg + k0,               &Bs[w * 32][0]);
    gl16(Bg + k0 + (long)16 * K, &Bs[w * 32 + 16][0]);
    __syncthreads();
    const int kq = (lane >> 4) ^ kqs;
    bfrag af[4], bf[4];
    #pragma unroll
    for (int i = 0; i < 4; ++i) af[i] = ldfrag(&As[wr + i * 16 + frow][kq * 8]);
    #pragma unroll
    for (int j = 0; j < 4; ++j) bf[j] = ldfrag(&Bs[wc + j * 16 + frow][kq * 8]);
    #pragma unroll
    for (int i = 0; i < 4; ++i)
      #pragma unroll
      for (int j = 0; j < 4; ++j)
        acc[i][j] = __builtin_amdgcn_mfma_f32_16x16x32_bf16(af[i], bf[j], acc[i][j], 0, 0, 0);
  }

  const int rb = (lane >> 4) * 4;
  if constexpr (STORE == ST_QKV) {
    const int sel = n0 >> 10;
    const int h = (n0 >> 7) & 7;
    ushort_t* __restrict__ Bq = (sel == 0) ? Q0 : ((sel == 1) ? Q1 : Q2);
    const int S = 1 << logS;
    #pragma unroll
    for (int i = 0; i < 4; ++i)
      #pragma unroll
      for (int j = 0; j < 4; ++j)
        #pragma unroll
        for (int e = 0; e < 4; ++e) {
          const int gm = m0 + wr + i * 16 + rb + e;
          const int dq = wc + j * 16 + frow;
          const int b = gm >> logS, s = gm & (S - 1);
          Bq[((long)(h * 16 + b) * S + (long)s) * 128 + dq] = f2bf(acc[i][j][e]);
        }
  } else {
    #pragma unroll
    for (int i = 0; i < 4; ++i)
      #pragma unroll
      for (int j = 0; j < 4; ++j)
        #pragma unroll
        for (int e = 0; e < 4; ++e) {
          const int gm = m0 + wr + i * 16 + rb + e;
          const int gn = n0 + wc + j * 16 + frow;
          float val = acc[i][j][e];
          if constexpr (STORE == ST_SWISH) val = val / (1.0f + __expf(-val));
          if constexpr (STORE == ST_BF16 || STORE == ST_SWISH) {
            Q0[(long)gm * N + gn] = f2bf(val);
          } else if constexpr (STORE == ST_F32RES) {
            Cf[(long)gm * N + gn] = val + Res[(long)gm * N + gn];
          } else if constexpr (STORE == ST_SCR) {
            const int b = z & 15, hh = z >> 4;
            Q0[(long)b * (ST * DIM) + (long)(hh * 128 + (gm >> 3)) * DIM +
               (gm & 7) * 128 + gn] = f2bf(val);
          }
        }
  }
}

// ---------------------------------------------------------------------------
// AmatT[z][e][d] = sum_s V[z][s][e] * softK[z][s][d]; bf16 in/out.
// ---------------------------------------------------------------------------
__global__ __launch_bounds__(256, 2)
void gemm_ktv(const ushort_t* __restrict__ Kp, const ushort_t* __restrict__ Vp,
              ushort_t* __restrict__ AT, int S)
{
  __shared__ ushort_t As[128][40];
  __shared__ ushort_t Bs[128][40];
  const int tid = threadIdx.x;
  const int z = blockIdx.x;
  const ushort_t* Vb = Vp + (long)z * S * DQh;
  const ushort_t* Kb = Kp + (long)z * S * DQh;
  const int lane = tid & 63;
  const int wr = ((tid >> 6) >> 1) * 64, wc = ((tid >> 6) & 1) * 64;
  const int frow = lane & 15, fk = (lane >> 4) * 8;
  const int c = tid & 127;
  const int sr0 = tid >> 7;

  f32x4 acc[4][4];
  #pragma unroll
  for (int i = 0; i < 4; ++i)
    #pragma unroll
    for (int j = 0; j < 4; ++j) acc[i][j] = f32x4{0.f, 0.f, 0.f, 0.f};

  for (int s0 = 0; s0 < S; s0 += 32) {
    __syncthreads();
    #pragma unroll
    for (int p = 0; p < 16; ++p) {
      const int sr = sr0 + p * 2;
      As[c][sr] = Vb[(long)(s0 + sr) * DQh + c];
      Bs[c][sr] = Kb[(long)(s0 + sr) * DQh + c];
    }
    __syncthreads();
    bfrag af[4], bfv[4];
    #pragma unroll
    for (int i = 0; i < 4; ++i) af[i]  = ldfrag(&As[wr + i * 16 + frow][fk]);
    #pragma unroll
    for (int j = 0; j < 4; ++j) bfv[j] = ldfrag(&Bs[wc + j * 16 + frow][fk]);
    #pragma unroll
    for (int i = 0; i < 4; ++i)
      #pragma unroll
      for (int j = 0; j < 4; ++j)
        acc[i][j] = __builtin_amdgcn_mfma_f32_16x16x32_bf16(af[i], bfv[j], acc[i][j], 0, 0, 0);
  }
  const int rb = (lane >> 4) * 4;
  #pragma unroll
  for (int i = 0; i < 4; ++i)
    #pragma unroll
    for (int j = 0; j < 4; ++j)
      #pragma unroll
      for (int e = 0; e < 4; ++e)
        AT[(long)z * 16384 + (long)(wr + i * 16 + rb + e) * 128 + (wc + j * 16 + frow)] =
            f2bf(acc[i][j][e]);
}

// ---------------------------------------------------------------------------
// Row softmax over 128 (head-dim), bf16 in/out, optional head-dim mask.
// ---------------------------------------------------------------------------
template<bool MASKED>
__global__ __launch_bounds__(256)
void softmax128(ushort_t* __restrict__ X, int smask)
{
  const int row = blockIdx.x * 4 + (threadIdx.x >> 6);
  const int lane = threadIdx.x & 63;
  ushort_t* xr = X + (long)row * 128;
  float x0 = bf2f(xr[lane]) * INV_SCALE;
  float x1 = bf2f(xr[lane + 64]) * INV_SCALE;
  if constexpr (MASKED) {
    const int s = row & smask;
    if (lane > s)      x0 = -3.0e38f;
    if (lane + 64 > s) x1 = -3.0e38f;
  }
  float mx = fmaxf(x0, x1);
  #pragma unroll
  for (int o = 32; o; o >>= 1) mx = fmaxf(mx, __shfl_xor(mx, o));
  const float e0 = __expf(x0 - mx);
  const float e1 = __expf(x1 - mx);
  float sm = e0 + e1;
  #pragma unroll
  for (int o = 32; o; o >>= 1) sm += __shfl_xor(sm, o);
  const float inv = 1.0f / sm;
  xr[lane]      = f2bf(e0 * inv);
  xr[lane + 64] = f2bf(e1 * inv);
}

// ---------------------------------------------------------------------------
// LayerNorm over DIM=1024, f32 in, f32 out + optional bf16 copy.
// ---------------------------------------------------------------------------
__global__ __launch_bounds__(256)
void layernorm_k(const float* __restrict__ X, const float* __restrict__ G,
                 const float* __restrict__ Bta, float* __restrict__ Y,
                 ushort_t* __restrict__ Yb)
{
  const int row = blockIdx.x;
  const int t = threadIdx.x;
  const float4 v = *(const float4*)(X + (long)row * DIM + t * 4);
  float s  = v.x + v.y + v.z + v.w;
  float sq = v.x * v.x + v.y * v.y + v.z * v.z + v.w * v.w;
  #pragma unroll
  for (int o = 32; o; o >>= 1) { s += __shfl_xor(s, o); sq += __shfl_xor(sq, o); }
  __shared__ float ps[4], pq[4];
  if ((t & 63) == 0) { ps[t >> 6] = s; pq[t >> 6] = sq; }
  __syncthreads();
  s  = ps[0] + ps[1] + ps[2] + ps[3];
  sq = pq[0] + pq[1] + pq[2] + pq[3];
  const float mean = s * (1.0f / DIM);
  const float var  = sq * (1.0f / DIM) - mean * mean;
  const float rstd = rsqrtf(var + LN_EPS);
  const float4 gv = *(const float4*)(G + t * 4);
  const float4 bv = *(const float4*)(Bta + t * 4);
  float4 o;
  o.x = (v.x - mean) * rstd * gv.x + bv.x;
  o.y = (v.y - mean) * rstd * gv.y + bv.y;
  o.z = (v.z - mean) * rstd * gv.z + bv.z;
  o.w = (v.w - mean) * rstd * gv.w + bv.w;
  *(float4*)(Y + (long)row * DIM + t * 4) = o;
  if (Yb) {
    ushort4 ob = make_ushort4(f2bf(o.x), f2bf(o.y), f2bf(o.z), f2bf(o.w));
    *(ushort4*)(Yb + (long)row * DIM + t * 4) = ob;
  }
}

// Weight prep: [H][DIM][DQh] f32 -> rows (h*128+dq), cols k, bf16
__global__ __launch_bounds__(256)
void transpose_cast(const float* __restrict__ W, ushort_t* __restrict__ Wt)
{
  __shared__ float tile[32][33];
  const int z = blockIdx.z;
  const int kb = blockIdx.y * 32;
  const int nb = blockIdx.x * 32;
  const float* src = W + (long)z * DIM * DQh;
  ushort_t* dst = Wt + (long)z * DIM * DQh;
  const int tx = threadIdx.x & 31;
  const int ty = threadIdx.x >> 5;
  #pragma unroll
  for (int r = 0; r < 32; r += 8)
    tile[ty + r][tx] = src[(long)(kb + ty + r) * DQh + nb + tx];
  __syncthreads();
  #pragma unroll
  for (int r = 0; r < 32; r += 8)
    dst[(long)(nb + ty + r) * DIM + kb + tx] = f2bf(tile[tx][ty + r]);
}

__global__ __launch_bounds__(256)
void cast_bf16(const float* __restrict__ X, ushort_t* __restrict__ Yq)
{
  const long i = ((long)blockIdx.x * 256 + threadIdx.x) * 4;
  const float4 v = *(const float4*)(X + i);
  ushort4 sv = make_ushort4(f2bf(v.x), f2bf(v.y), f2bf(v.z), f2bf(v.w));
  *(ushort4*)(Yq + i) = sv;
}

// ---------------------------------------------------------------------------

extern "C" void kernel_launch(void* const* d_in, const int* in_sizes, int n_in,
                              void* d_out, int out_size, void* d_ws, size_t ws_size,
                              hipStream_t stream)
{
  (void)in_sizes; (void)n_in; (void)out_size; (void)ws_size;
  const float* mem = (const float*)d_in[0];
  const float* y0  = (const float*)d_in[1];
  const float* Wq1 = (const float*)d_in[2];
  const float* Wk1 = (const float*)d_in[3];
  const float* Wv1 = (const float*)d_in[4];
  const float* Wo1 = (const float*)d_in[5];
  const float* Wq2 = (const float*)d_in[6];
  const float* Wk2 = (const float*)d_in[7];
  const float* Wv2 = (const float*)d_in[8];
  const float* Wo2 = (const float*)d_in[9];
  const float* E1  = (const float*)d_in[10];
  const float* D1  = (const float*)d_in[11];
  const float* E2  = (const float*)d_in[12];
  const float* D2  = (const float*)d_in[13];
  const float* g1  = (const float*)d_in[14];
  const float* b1  = (const float*)d_in[15];
  const float* g2  = (const float*)d_in[16];
  const float* b2  = (const float*)d_in[17];
  const float* g3  = (const float*)d_in[18];
  const float* b3  = (const float*)d_in[19];

  char* ws = (char*)d_ws;
  const size_t MB = 1ull << 20;
  ushort_t* wcat1 = (ushort_t*)(ws + 0 * MB);    // [3072][1024] Q|K|V phase1
  ushort_t* wkv2  = (ushort_t*)(ws + 6 * MB);    // [2048][1024] K|V phase2
  ushort_t* wq2t  = (ushort_t*)(ws + 10 * MB);   // [1024][1024]
  ushort_t* wo1b  = (ushort_t*)(ws + 12 * MB);
  ushort_t* wo2b  = (ushort_t*)(ws + 14 * MB);
  ushort_t* e1b   = (ushort_t*)(ws + 16 * MB);
  ushort_t* d1b   = (ushort_t*)(ws + 17 * MB);
  ushort_t* e2b   = (ushort_t*)(ws + 18 * MB);
  ushort_t* d2b   = (ushort_t*)(ws + 19 * MB);
  ushort_t* y0b   = (ushort_t*)(ws + 20 * MB);   // 32 MB
  ushort_t* memb  = (ushort_t*)(ws + 52 * MB);   // 64 MB
  ushort_t* qbuf  = (ushort_t*)(ws + 116 * MB);  // [128][1024][128]  32 MB
  ushort_t* kbuf  = (ushort_t*)(ws + 148 * MB);  // [128][2048][128]  64 MB
  ushort_t* vbuf  = (ushort_t*)(ws + 212 * MB);  // 64 MB
  ushort_t* amatT = (ushort_t*)(ws + 276 * MB);  // [128][128][128]    4 MB
  ushort_t* attnb = (ushort_t*)(ws + 280 * MB);  // [16][1024][1024]  32 MB
  float*    ybuf  = (float*)(ws + 312 * MB);     // 64 MB
  ushort_t* ybf   = (ushort_t*)(ws + 376 * MB);  // 32 MB
  ushort_t* hbuf  = (ushort_t*)(ws + 408 * MB);  // 32 MB
  ushort_t* bn1   = attnb;                       // reuse (16 MB)
  ushort_t* bn2   = qbuf;                        // reuse (16 MB)

  // ---- prep ----
  cast_bf16<<<16384, 256, 0, stream>>>(y0, y0b);
  cast_bf16<<<32768, 256, 0, stream>>>(mem, memb);
  transpose_cast<<<dim3(4, 32, 8), 256, 0, stream>>>(Wq1, wcat1);
  transpose_cast<<<dim3(4, 32, 8), 256, 0, stream>>>(Wk1, wcat1 + (1 << 20));
  transpose_cast<<<dim3(4, 32, 8), 256, 0, stream>>>(Wv1, wcat1 + (2 << 20));
  transpose_cast<<<dim3(4, 32, 8), 256, 0, stream>>>(Wk2, wkv2);
  transpose_cast<<<dim3(4, 32, 8), 256, 0, stream>>>(Wv2, wkv2 + (1 << 20));
  transpose_cast<<<dim3(4, 32, 8), 256, 0, stream>>>(Wq2, wq2t);
  cast_bf16<<<1024, 256, 0, stream>>>(Wo1, wo1b);
  cast_bf16<<<1024, 256, 0, stream>>>(Wo2, wo2b);
  cast_bf16<<<512, 256, 0, stream>>>(E1, e1b);
  cast_bf16<<<512, 256, 0, stream>>>(D1, d1b);
  cast_bf16<<<512, 256, 0, stream>>>(E2, e2b);
  cast_bf16<<<512, 256, 0, stream>>>(D2, d2b);

  // ---- phase 1: masked self linear-attention ----
  gemm_bb<ST_QKV><<<dim3(24, 128, 1), 256, 0, stream>>>(
      y0b, wcat1, nullptr, qbuf, kbuf, vbuf, nullptr,
      NB * ST, 3072, DIM, 0, 0, 10);
  softmax128<true><<<NH * NB * ST / 4, 256, 0, stream>>>(qbuf, ST - 1);
  softmax128<false><<<NH * NB * ST / 4, 256, 0, stream>>>(kbuf, 0);
  gemm_ktv<<<NH * NB, 256, 0, stream>>>(kbuf, vbuf, amatT, ST);
  gemm_bb<ST_SCR><<<dim3(1, 8, 128), 256, 0, stream>>>(
      qbuf, amatT, nullptr, attnb, nullptr, nullptr, nullptr,
      ST, DQh, DQh, (long)ST * DQh, 16384, 0);
  gemm_bb<ST_F32RES><<<dim3(8, 128, 1), 256, 0, stream>>>(
      attnb, wo1b, y0, nullptr, nullptr, nullptr, ybuf,
      NB * ST, DIM, DIM, 0, 0, 0);
  layernorm_k<<<NB * ST, 256, 0, stream>>>(ybuf, g1, b1, ybuf, ybf);

  // ---- phase 2: cross linear-attention ----
  gemm_bb<ST_QKV><<<dim3(8, 128, 1), 256, 0, stream>>>(
      ybf, wq2t, nullptr, qbuf, nullptr, nullptr, nullptr,
      NB * ST, 1024, DIM, 0, 0, 10);
  gemm_bb<ST_QKV><<<dim3(16, 256, 1), 256, 0, stream>>>(
      memb, wkv2, nullptr, kbuf, vbuf, nullptr, nullptr,
      NB * SM, 2048, DIM, 0, 0, 11);
  softmax128<false><<<NH * NB * ST / 4, 256, 0, stream>>>(qbuf, 0);
  softmax128<false><<<NH * NB * SM / 4, 256, 0, stream>>>(kbuf, 0);
  gemm_ktv<<<NH * NB, 256, 0, stream>>>(kbuf, vbuf, amatT, SM);
  gemm_bb<ST_SCR><<<dim3(1, 8, 128), 256, 0, stream>>>(
      qbuf, amatT, nullptr, attnb, nullptr, nullptr, nullptr,
      ST, DQh, DQh, (long)ST * DQh, 16384, 0);
  gemm_bb<ST_F32RES><<<dim3(8, 128, 1), 256, 0, stream>>>(
      attnb, wo2b, ybuf, nullptr, nullptr, nullptr, ybuf,
      NB * ST, DIM, DIM, 0, 0, 0);
  layernorm_k<<<NB * ST, 256, 0, stream>>>(ybuf, g2, b2, ybuf, ybf);

  // ---- phase 3: LFFN ----
  gemm_bb<ST_BF16><<<dim3(4, 128, 1), 256, 0, stream>>>(
      ybf, e1b, nullptr, bn1, nullptr, nullptr, nullptr,
      NB * ST, 512, DIM, 0, 0, 0);
  gemm_bb<ST_SWISH><<<dim3(8, 128, 1), 256, 0, stream>>>(
      bn1, d1b, nullptr, hbuf, nullptr, nullptr, nullptr,
      NB * ST, DIM, 512, 0, 0, 0);
  gemm_bb<ST_BF16><<<dim3(4, 128, 1), 256, 0, stream>>>(
      hbuf, e2b, nullptr, bn2, nullptr, nullptr, nullptr,
      NB * ST, 512, DIM, 0, 0, 0);
  gemm_bb<ST_F32RES><<<dim3(8, 128, 1), 256, 0, stream>>>(
      bn2, d2b, ybuf, nullptr, nullptr, nullptr, ybuf,
      NB * ST, DIM, 512, 0, 0, 0);
  layernorm_k<<<NB * ST, 256, 0, stream>>>(ybuf, g3, b3, (float*)d_out, nullptr);
}